// Round 1
// baseline (2092.334 us; speedup 1.0000x reference)
//
#include <hip/hip_runtime.h>
#include <math.h>

#define STEPS 37
#define NMAT  (STEPS*STEPS + 1)   // 1370 (CLS + 37x37 grid)
#define D     128
#define MSIZE (D*D)               // 16384 floats = 64 KB

// acc[i][j] = sign * sum_k At[k][r0+i] * Bm[k][c0+j]
// At is a transposed-layout operand in LDS (row k contiguous in memory).
template<int NEG>
__device__ __forceinline__ void mm_accum(const float* __restrict__ At,
                                         const float* __restrict__ Bm,
                                         int r0, int c0, float acc[8][8])
{
    #pragma unroll
    for (int i = 0; i < 8; ++i)
        #pragma unroll
        for (int j = 0; j < 8; ++j) acc[i][j] = 0.0f;

    #pragma unroll 2
    for (int k = 0; k < D; ++k) {
        const float4 a0 = *reinterpret_cast<const float4*>(&At[k*D + r0]);
        const float4 a1 = *reinterpret_cast<const float4*>(&At[k*D + r0 + 4]);
        const float4 b0 = *reinterpret_cast<const float4*>(&Bm[k*D + c0]);
        const float4 b1 = *reinterpret_cast<const float4*>(&Bm[k*D + c0 + 4]);
        const float a[8] = {a0.x, a0.y, a0.z, a0.w, a1.x, a1.y, a1.z, a1.w};
        const float b[8] = {b0.x, b0.y, b0.z, b0.w, b1.x, b1.y, b1.z, b1.w};
        #pragma unroll
        for (int i = 0; i < 8; ++i)
            #pragma unroll
            for (int j = 0; j < 8; ++j)
                acc[i][j] = fmaf(a[i], b[j], acc[i][j]);
    }
    if (NEG) {
        #pragma unroll
        for (int i = 0; i < 8; ++i)
            #pragma unroll
            for (int j = 0; j < 8; ++j) acc[i][j] = -acc[i][j];
    }
}

__global__ __launch_bounds__(256)
void liere_expm_kernel(const float* __restrict__ gen, float* __restrict__ out)
{
    // Bs: B (scaled generator) during Horner phase, then X^T during squaring.
    // Xs: running matrix X.
    __shared__ float Bs[MSIZE];
    __shared__ float Xs[MSIZE];
    __shared__ float red[132];

    const int tid = threadIdx.x;   // 0..255
    const int wg  = blockIdx.x;    // 0..1369

    // position (wg==0 is the CLS token: G = 0 -> expm = I, handled naturally)
    float px = 0.0f, py = 0.0f;
    if (wg > 0) {
        const int idx = wg - 1;
        px = (float)(idx / STEPS) * (1.0f / (STEPS - 1));
        py = (float)(idx % STEPS) * (1.0f / (STEPS - 1));
    }

    // ---- build G = px*skew0 + py*skew1 into Bs (exactly skew-symmetric) ----
    const float* __restrict__ g0 = gen;
    const float* __restrict__ g1 = gen + MSIZE;
    for (int e = tid; e < MSIZE; e += 256) {
        const int i = e >> 7, j = e & 127;
        float v = 0.0f;
        if (i < j)      v =  (px * g0[e] + py * g1[e]);
        else if (i > j) v = -(px * g0[j*D + i] + py * g1[j*D + i]);
        Bs[e] = v;
    }
    __syncthreads();

    // ---- 1-norm (max column abs-sum), squaring count, scale B <- B/2^s ----
    if (tid < D) {
        float s = 0.0f;
        for (int i = 0; i < D; ++i) s += fabsf(Bs[i*D + tid]);
        red[tid] = s;
    }
    __syncthreads();
    if (tid == 0) {
        float m = 0.0f;
        for (int j = 0; j < D; ++j) m = fmaxf(m, red[j]);
        int s = 0;
        if (m > 1.0f) s = (int)ceilf(log2f(m));
        if (s < 0) s = 0;
        red[128] = (float)s;
        red[129] = exp2f(-(float)s);
    }
    __syncthreads();
    const int nsq = (int)red[128];
    {
        const float sc = red[129];
        for (int e = tid; e < MSIZE; e += 256) Bs[e] *= sc;   // exact (power of 2)
    }
    __syncthreads();

    // Taylor coefficients 1/k!
    const float C[13] = {
        1.0f, 1.0f, 5.0e-1f, 1.6666666666666666e-1f, 4.1666666666666664e-2f,
        8.3333333333333332e-3f, 1.3888888888888889e-3f, 1.9841269841269841e-4f,
        2.4801587301587302e-5f, 2.7557319223985893e-6f, 2.7557319223985888e-7f,
        2.5052108385441720e-8f, 2.0876756987868099e-9f };

    // ---- init X = C12*B + C11*I ----
    for (int e = tid; e < MSIZE; e += 256) {
        const int i = e >> 7, j = e & 127;
        Xs[e] = fmaf(C[12], Bs[e], (i == j ? C[11] : 0.0f));
    }
    __syncthreads();

    const int ty = tid >> 4, tx = tid & 15;
    const int r0 = ty << 3, c0 = tx << 3;
    float acc[8][8];

    // ---- Horner: X <- B*X + C[kk]*I, kk = 10..0 ----
    // A-side uses skew-symmetry: B[r][k] = -Bs[k*D + r] (row-contiguous read),
    // so acc = -(B*X); sign fixed in epilogue (exact).
    for (int kk = 10; kk >= 0; --kk) {
        mm_accum<1>(Bs, Xs, r0, c0, acc);
        __syncthreads();                       // all reads done before overwrite
        const bool last = (kk == 0);
        #pragma unroll
        for (int i = 0; i < 8; ++i) {
            const int r = r0 + i;
            #pragma unroll
            for (int j = 0; j < 8; ++j) {
                const int c = c0 + j;
                const float v = (r == c ? C[kk] : 0.0f) + acc[i][j];
                Xs[r*D + c] = v;
                if (last) Bs[c*D + r] = v;     // build X^T for squaring phase
            }
        }
        __syncthreads();
    }

    // ---- squaring: X <- X*X, nsq times; last one streams straight to HBM ----
    float* __restrict__ o = out + (size_t)wg * MSIZE;
    for (int t = 0; t < nsq; ++t) {
        mm_accum<0>(Bs, Xs, r0, c0, acc);      // Bs holds X^T: acc = +(X*X)
        __syncthreads();
        if (t + 1 < nsq) {
            #pragma unroll
            for (int i = 0; i < 8; ++i) {
                const int r = r0 + i;
                #pragma unroll
                for (int j = 0; j < 8; ++j) {
                    const int c = c0 + j;
                    const float v = acc[i][j];
                    Xs[r*D + c] = v;
                    Bs[c*D + r] = v;
                }
            }
            __syncthreads();
        } else {
            #pragma unroll
            for (int i = 0; i < 8; ++i) {
                const float4 v0 = make_float4(acc[i][0], acc[i][1], acc[i][2], acc[i][3]);
                const float4 v1 = make_float4(acc[i][4], acc[i][5], acc[i][6], acc[i][7]);
                *reinterpret_cast<float4*>(&o[(r0 + i)*D + c0])     = v0;
                *reinterpret_cast<float4*>(&o[(r0 + i)*D + c0 + 4]) = v1;
            }
        }
    }
    if (nsq == 0) {
        for (int e = tid; e < MSIZE; e += 256) o[e] = Xs[e];
    }
}

extern "C" void kernel_launch(void* const* d_in, const int* in_sizes, int n_in,
                              void* d_out, int out_size, void* d_ws, size_t ws_size,
                              hipStream_t stream) {
    (void)in_sizes; (void)n_in; (void)d_ws; (void)ws_size; (void)out_size;
    const float* gen = (const float*)d_in[1];   // [2,1,128,128] fp32
    float* out = (float*)d_out;                 // [1,1370,1,128,128] fp32
    liere_expm_kernel<<<NMAT, 256, 0, stream>>>(gen, out);
}

// Round 2
// 655.306 us; speedup vs baseline: 3.1929x; 3.1929x over previous
//
#include <hip/hip_runtime.h>
#include <math.h>

#define STEPS 37
#define NMAT  (STEPS*STEPS + 1)   // 1370
#define D     128

typedef _Float16 half8 __attribute__((ext_vector_type(8)));
typedef float    f32x4 __attribute__((ext_vector_type(4)));

// LDS layout (bytes). fp16 matrices have padded rows: 128*2B + 16B pad = 272B
// (ROWH = 136 half-elements) -> all b128/b64 accesses land 2-way-max on banks.
#define ROWH     136
#define PH_OFF   0            // P (scaled generator) high halves; later X row-major high
#define PL_OFF   34816        // P low (pre-scaled by 2^11);     later X row-major low
#define QTH_OFF  69632        // X^T high halves (cols of X, K-contiguous)
#define QTL_OFF  104448       // X^T low
#define RED_OFF  139264
#define LDS_BYTES (139264 + 640)

__constant__ float dC[13] = {
    1.0f, 1.0f, 5.0e-1f, 1.6666666666666666e-1f, 4.1666666666666664e-2f,
    8.3333333333333332e-3f, 1.3888888888888889e-3f, 1.9841269841269841e-4f,
    2.4801587301587302e-5f, 2.7557319223985893e-6f, 2.7557319223985888e-7f,
    2.5052108385441720e-8f, 2.0876756987868099e-9f };

// One step:  Y = A * X  (+ diagc*I).  A is (PH,PL) area row-major K-contig;
// X is read from (QTH,QTL) = X^T row-major K-contig.
// Output: optionally new X^T (WQT), new X row-major (WXR), global fp32 (WGL).
template<bool WQT, bool WXR, bool WGL>
__device__ __forceinline__ void matmul_step(unsigned char* sm, float diagc,
                                            float* __restrict__ gout,
                                            int wr, int wc, int lr, int g)
{
    const _Float16* Ah = (const _Float16*)(sm + PH_OFF);
    const _Float16* Al = (const _Float16*)(sm + PL_OFF);
    const _Float16* Bh = (const _Float16*)(sm + QTH_OFF);
    const _Float16* Bl = (const _Float16*)(sm + QTL_OFF);

    f32x4 acc1[4][4] = {};   // h*h
    f32x4 acc2[4][4] = {};   // h*l' + l'*h   (l' = l * 2^11)

    #pragma unroll
    for (int ks = 0; ks < 4; ++ks) {
        const int kof = 32*ks + 8*g;            // half-element offset within row
        half8 ah[4], al[4];
        #pragma unroll
        for (int bi = 0; bi < 4; ++bi) {
            const int r = wr*64 + bi*16 + lr;
            ah[bi] = *(const half8*)&Ah[r*ROWH + kof];
            al[bi] = *(const half8*)&Al[r*ROWH + kof];
        }
        #pragma unroll
        for (int bj = 0; bj < 4; ++bj) {
            const int c = wc*64 + bj*16 + lr;
            const half8 qh = *(const half8*)&Bh[c*ROWH + kof];
            const half8 ql = *(const half8*)&Bl[c*ROWH + kof];
            #pragma unroll
            for (int bi = 0; bi < 4; ++bi) {
                acc1[bi][bj] = __builtin_amdgcn_mfma_f32_16x16x32_f16(ah[bi], qh, acc1[bi][bj], 0, 0, 0);
                acc2[bi][bj] = __builtin_amdgcn_mfma_f32_16x16x32_f16(ah[bi], ql, acc2[bi][bj], 0, 0, 0);
                acc2[bi][bj] = __builtin_amdgcn_mfma_f32_16x16x32_f16(al[bi], qh, acc2[bi][bj], 0, 0, 0);
            }
        }
    }
    __syncthreads();   // all reads of P/X done before overwriting

    _Float16* WQh = (_Float16*)(sm + QTH_OFF);
    _Float16* WQl = (_Float16*)(sm + QTL_OFF);
    _Float16* WXh = (_Float16*)(sm + PH_OFF);
    _Float16* WXl = (_Float16*)(sm + PL_OFF);

    #pragma unroll
    for (int bi = 0; bi < 4; ++bi) {
        #pragma unroll
        for (int bj = 0; bj < 4; ++bj) {
            const int col = wc*64 + bj*16 + lr;       // D col = lane&15
            const int r0  = wr*64 + bi*16 + 4*g;      // D rows = 4*(lane>>4)+q
            union { _Float16 h[4]; uint2 u; } uh, ul;
            float vv[4];
            #pragma unroll
            for (int q = 0; q < 4; ++q) {
                float v = acc1[bi][bj][q] + acc2[bi][bj][q] * (1.0f/2048.0f);
                if (r0 + q == col) v += diagc;
                vv[q] = v;
                _Float16 h = (_Float16)v;
                uh.h[q] = h;
                ul.h[q] = (_Float16)((v - (float)h) * 2048.0f);
            }
            if (WQT) {   // X^T: 4 consecutive rows at fixed col -> one b64 each
                *(uint2*)&WQh[col*ROWH + r0] = uh.u;
                *(uint2*)&WQl[col*ROWH + r0] = ul.u;
            }
            if (WXR) {   // X row-major: scattered u16 (transpose cost)
                #pragma unroll
                for (int q = 0; q < 4; ++q) {
                    WXh[(r0+q)*ROWH + col] = uh.h[q];
                    WXl[(r0+q)*ROWH + col] = ul.h[q];
                }
            }
            if (WGL) {
                #pragma unroll
                for (int q = 0; q < 4; ++q) gout[(r0+q)*D + col] = vv[q];
            }
        }
    }
    __syncthreads();   // writes visible before next step's reads
}

__global__ __launch_bounds__(256, 1)
void liere_expm_mfma(const float* __restrict__ gen, float* __restrict__ out)
{
    __shared__ __align__(16) unsigned char sm[LDS_BYTES];
    const int tid = threadIdx.x;
    const int wg  = blockIdx.x;

    float px = 0.f, py = 0.f;
    if (wg > 0) {
        const int idx = wg - 1;
        px = (float)(idx / STEPS) * (1.0f/(STEPS-1));
        py = (float)(idx % STEPS) * (1.0f/(STEPS-1));
    }

    // ---- Phase 0: G = px*S0 + py*S1 (fp32) into QT area, padded 132-float rows
    float* Gp = (float*)(sm + QTH_OFF);
    const float* g0 = gen;
    const float* g1 = gen + D*D;
    for (int it = 0; it < 64; ++it) {
        const int e = tid + (it << 8);
        const int i = e >> 7, j = e & 127;
        if (i < j) {
            const float v = px*g0[e] + py*g1[e];   // coalesced upper-tri read
            Gp[i*132 + j] =  v;
            Gp[j*132 + i] = -v;
        } else if (i == j) {
            Gp[i*132 + j] = 0.f;
        }
    }
    __syncthreads();

    // ---- Phase 1: 1-norm -> squaring count (theta = 2: one fewer squaring)
    float* red = (float*)(sm + RED_OFF);
    if (tid < D) {
        float s = 0.f;
        for (int i = 0; i < D; ++i) s += fabsf(Gp[i*132 + tid]);
        red[tid] = s;
    }
    __syncthreads();
    if (tid == 0) {
        float m = 0.f;
        for (int j = 0; j < D; ++j) m = fmaxf(m, red[j]);
        int s = 0;
        if (m > 2.f) s = (int)ceilf(log2f(m)) - 1;
        if (s < 0) s = 0;
        red[128] = (float)s;
        red[129] = exp2f(-(float)s);
    }
    __syncthreads();
    const int   nsq   = (int)red[128];
    const float scale = red[129];

    // ---- Phase A: stash this lane's 64 G values (QT area is about to be reused)
    float vst[64];
    #pragma unroll
    for (int it = 0; it < 64; ++it) {
        const int e = tid + (it << 8);
        vst[it] = Gp[(e>>7)*132 + (e&127)];
    }
    __syncthreads();

    // ---- Phase B: split P = G*2^-s into fp16 (h, l*2^11); init X = c12*P + c11*I
    {
        _Float16* Ph = (_Float16*)(sm + PH_OFF);
        _Float16* Pl = (_Float16*)(sm + PL_OFF);
        _Float16* Qh = (_Float16*)(sm + QTH_OFF);
        _Float16* Ql = (_Float16*)(sm + QTL_OFF);
        const float c12 = dC[12], c11 = dC[11];
        #pragma unroll
        for (int it = 0; it < 64; ++it) {
            const int e = tid + (it << 8);
            const int i = e >> 7, j = e & 127;
            const float p = vst[it] * scale;
            const _Float16 ph = (_Float16)p;
            const _Float16 pl = (_Float16)((p - (float)ph) * 2048.f);
            Ph[i*ROWH + j] = ph;
            Pl[i*ROWH + j] = pl;
            const float x = c12*p + ((i == j) ? c11 : 0.f);
            const _Float16 xh = (_Float16)x;
            const _Float16 xl = (_Float16)((x - (float)xh) * 2048.f);
            Qh[j*ROWH + i] = xh;   // X^T
            Ql[j*ROWH + i] = xl;
        }
    }
    __syncthreads();

    const int lid = tid & 63;
    const int wid = tid >> 6;
    const int wr = wid >> 1, wc = wid & 1;
    const int lr = lid & 15, g = lid >> 4;
    float* gout = out + (size_t)wg * (D*D);

    // ---- Horner: X <- P*X + c_k*I (degree-12 Taylor, theta=2)
    for (int kk = 10; kk >= 1; --kk)
        matmul_step<true, false, false>(sm, dC[kk], gout, wr, wc, lr, g);
    // last Horner step also materializes X row-major for the squaring phase
    matmul_step<true, true, false>(sm, dC[0], gout, wr, wc, lr, g);

    if (nsq == 0) {   // tiny-norm blocks (incl. CLS): X is the answer
        const _Float16* Xh = (const _Float16*)(sm + PH_OFF);
        const _Float16* Xl = (const _Float16*)(sm + PL_OFF);
        for (int it = 0; it < 64; ++it) {
            const int e = tid + (it << 8);
            const int i = e >> 7, j = e & 127;
            gout[e] = (float)Xh[i*ROWH + j] + (float)Xl[i*ROWH + j] * (1.0f/2048.0f);
        }
        return;
    }

    // ---- Squarings: X <- X*X; last one streams fp32 straight to HBM
    for (int t = 0; t < nsq - 1; ++t)
        matmul_step<true, true, false>(sm, 0.f, gout, wr, wc, lr, g);
    matmul_step<false, false, true>(sm, 0.f, gout, wr, wc, lr, g);
}

extern "C" void kernel_launch(void* const* d_in, const int* in_sizes, int n_in,
                              void* d_out, int out_size, void* d_ws, size_t ws_size,
                              hipStream_t stream) {
    (void)in_sizes; (void)n_in; (void)d_ws; (void)ws_size; (void)out_size;
    const float* gen = (const float*)d_in[1];   // [2,1,128,128] fp32
    float* out = (float*)d_out;                 // [1,1370,1,128,128] fp32
    liere_expm_mfma<<<NMAT, 256, 0, stream>>>(gen, out);
}

// Round 4
// 514.349 us; speedup vs baseline: 4.0679x; 1.2740x over previous
//
#include <hip/hip_runtime.h>
#include <math.h>

#define STEPS 37
#define NMAT  (STEPS*STEPS + 1)   // 1370
#define D     128
#define NT    512                 // 8 waves, 2 per SIMD

typedef _Float16 half8 __attribute__((ext_vector_type(8)));
typedef __fp16   fp16x2 __attribute__((ext_vector_type(2)));
typedef float    f32x4 __attribute__((ext_vector_type(4)));

// LDS layout (bytes). fp16 matrices padded: 128*2B + 16B = 272B rows (ROWH=136)
#define ROWH     136
#define PH_OFF   0            // P high; later X row-major high
#define PL_OFF   34816        // P low (pre-scaled 2^11); later X row-major low
#define QTH_OFF  69632        // X^T high (cols of X, K-contiguous)
#define QTL_OFF  104448       // X^T low
#define RED_OFF  139264
#define LDS_BYTES (139264 + 640)

__constant__ float dC[13] = {
    1.0f, 1.0f, 5.0e-1f, 1.6666666666666666e-1f, 4.1666666666666664e-2f,
    8.3333333333333332e-3f, 1.3888888888888889e-3f, 1.9841269841269841e-4f,
    2.4801587301587302e-5f, 2.7557319223985893e-6f, 2.7557319223985888e-7f,
    2.5052108385441720e-8f, 2.0876756987868099e-9f };

// Y = A*X (+ diagc*I). A rows from PH/PL; X cols from QTH/QTL (stored as X^T rows).
// 8-wave decomposition: wave (wr,wc) owns rows [wr*64,+64) x cols [wc*32,+32):
// bi in 0..3 (16-row blocks), bj in 0..1 (16-col blocks).
template<bool WQT, bool WXR, bool WGL>
__device__ __forceinline__ void matmul_step(unsigned char* sm, float diagc,
                                            float* __restrict__ gout,
                                            int wr, int wc, int lr, int g)
{
    const _Float16* Ah = (const _Float16*)(sm + PH_OFF);
    const _Float16* Al = (const _Float16*)(sm + PL_OFF);
    const _Float16* Bh = (const _Float16*)(sm + QTH_OFF);
    const _Float16* Bl = (const _Float16*)(sm + QTL_OFF);

    f32x4 acc1[4][2] = {};   // h*h
    f32x4 acc2[4][2] = {};   // h*l' + l'*h   (l' = l * 2^11)

    #pragma unroll
    for (int ks = 0; ks < 4; ++ks) {
        const int kof = 32*ks + 8*g;
        half8 ah[4], al[4];
        #pragma unroll
        for (int bi = 0; bi < 4; ++bi) {
            const int r = wr*64 + bi*16 + lr;
            ah[bi] = *(const half8*)&Ah[r*ROWH + kof];
            al[bi] = *(const half8*)&Al[r*ROWH + kof];
        }
        #pragma unroll
        for (int bj = 0; bj < 2; ++bj) {
            const int c = wc*32 + bj*16 + lr;
            const half8 qh = *(const half8*)&Bh[c*ROWH + kof];
            const half8 ql = *(const half8*)&Bl[c*ROWH + kof];
            #pragma unroll
            for (int bi = 0; bi < 4; ++bi) {
                acc1[bi][bj] = __builtin_amdgcn_mfma_f32_16x16x32_f16(ah[bi], qh, acc1[bi][bj], 0, 0, 0);
                acc2[bi][bj] = __builtin_amdgcn_mfma_f32_16x16x32_f16(ah[bi], ql, acc2[bi][bj], 0, 0, 0);
                acc2[bi][bj] = __builtin_amdgcn_mfma_f32_16x16x32_f16(al[bi], qh, acc2[bi][bj], 0, 0, 0);
            }
        }
    }

    if (WGL) {
        // Last step: combine and stream fp32 to HBM. No LDS writes -> no barriers.
        #pragma unroll
        for (int bi = 0; bi < 4; ++bi)
            #pragma unroll
            for (int bj = 0; bj < 2; ++bj) {
                const int col = wc*32 + bj*16 + lr;
                const int r0  = wr*64 + bi*16 + 4*g;
                #pragma unroll
                for (int q = 0; q < 4; ++q)
                    gout[(r0+q)*D + col] = acc1[bi][bj][q] + acc2[bi][bj][q] * (1.0f/2048.0f);
            }
        return;
    }

    // Register-only split conversion BEFORE the barrier (overlaps other waves' MFMAs)
    uint2 uhv[4][2], ulv[4][2];
    #pragma unroll
    for (int bi = 0; bi < 4; ++bi) {
        #pragma unroll
        for (int bj = 0; bj < 2; ++bj) {
            const int col = wc*32 + bj*16 + lr;
            const int r0  = wr*64 + bi*16 + 4*g;
            float v[4];
            #pragma unroll
            for (int q = 0; q < 4; ++q)
                v[q] = acc1[bi][bj][q] + acc2[bi][bj][q] * (1.0f/2048.0f);
            if (wr*64 + bi*16 == wc*32 + bj*16) {   // wave-uniform: tile holds diagonal
                #pragma unroll
                for (int q = 0; q < 4; ++q)
                    if (r0 + q == col) v[q] += diagc;
            }
            const fp16x2 h01 = __builtin_amdgcn_cvt_pkrtz(v[0], v[1]);
            const fp16x2 h23 = __builtin_amdgcn_cvt_pkrtz(v[2], v[3]);
            const fp16x2 l01 = __builtin_amdgcn_cvt_pkrtz((v[0]-(float)h01[0])*2048.f,
                                                          (v[1]-(float)h01[1])*2048.f);
            const fp16x2 l23 = __builtin_amdgcn_cvt_pkrtz((v[2]-(float)h23[0])*2048.f,
                                                          (v[3]-(float)h23[1])*2048.f);
            union { fp16x2 h2[2]; uint2 u; } cvh, cvl;
            cvh.h2[0] = h01; cvh.h2[1] = h23;
            cvl.h2[0] = l01; cvl.h2[1] = l23;
            uhv[bi][bj] = cvh.u; ulv[bi][bj] = cvl.u;
        }
    }
    __syncthreads();   // all reads of P/X done before overwrite

    _Float16* WQh = (_Float16*)(sm + QTH_OFF);
    _Float16* WQl = (_Float16*)(sm + QTL_OFF);
    _Float16* WXh = (_Float16*)(sm + PH_OFF);
    _Float16* WXl = (_Float16*)(sm + PL_OFF);
    #pragma unroll
    for (int bi = 0; bi < 4; ++bi) {
        #pragma unroll
        for (int bj = 0; bj < 2; ++bj) {
            const int col = wc*32 + bj*16 + lr;
            const int r0  = wr*64 + bi*16 + 4*g;
            if (WQT) {   // X^T: 4 consecutive rows at fixed col -> one b64 each
                *(uint2*)&WQh[col*ROWH + r0] = uhv[bi][bj];
                *(uint2*)&WQl[col*ROWH + r0] = ulv[bi][bj];
            }
            if (WXR) {   // X row-major: scattered u16 (transpose cost)
                union { uint2 u; _Float16 h[4]; } th, tl;
                th.u = uhv[bi][bj]; tl.u = ulv[bi][bj];
                #pragma unroll
                for (int q = 0; q < 4; ++q) {
                    WXh[(r0+q)*ROWH + col] = th.h[q];
                    WXl[(r0+q)*ROWH + col] = tl.h[q];
                }
            }
        }
    }
    __syncthreads();   // writes visible before next step's reads
}

__global__ __launch_bounds__(NT, 1)
void liere_expm_mfma(const float* __restrict__ gen, float* __restrict__ out)
{
    __shared__ __align__(16) unsigned char sm[LDS_BYTES];
    const int tid = threadIdx.x;
    const int wg  = blockIdx.x;

    float px = 0.f, py = 0.f;
    if (wg > 0) {
        const int idx = wg - 1;
        px = (float)(idx / STEPS) * (1.0f/(STEPS-1));
        py = (float)(idx % STEPS) * (1.0f/(STEPS-1));
    }

    // ---- Phase 0: G = px*S0 + py*S1 (fp32) into QT area, padded 132-float rows
    float* Gp = (float*)(sm + QTH_OFF);
    const float* g0 = gen;
    const float* g1 = gen + D*D;
    for (int it = 0; it < 32; ++it) {
        const int e = tid + (it << 9);
        const int i = e >> 7, j = e & 127;
        if (i < j) {
            const float v = px*g0[e] + py*g1[e];
            Gp[i*132 + j] =  v;
            Gp[j*132 + i] = -v;
        } else if (i == j) {
            Gp[i*132 + j] = 0.f;
        }
    }
    __syncthreads();

    // ---- Phase 1: 1-norm -> squaring count (theta = 2)
    float* red = (float*)(sm + RED_OFF);
    if (tid < D) {
        float s = 0.f;
        for (int i = 0; i < D; ++i) s += fabsf(Gp[i*132 + tid]);
        red[tid] = s;
    }
    __syncthreads();
    if (tid == 0) {
        float m = 0.f;
        for (int j = 0; j < D; ++j) m = fmaxf(m, red[j]);
        int s = 0;
        if (m > 2.f) s = (int)ceilf(log2f(m)) - 1;
        if (s < 0) s = 0;
        red[128] = (float)s;
        red[129] = exp2f(-(float)s);
    }
    __syncthreads();
    const int   nsq   = (int)red[128];
    const float scale = red[129];

    // ---- Phase A: stash this lane's G values (QT area about to be reused)
    float vst[32];
    #pragma unroll
    for (int it = 0; it < 32; ++it) {
        const int e = tid + (it << 9);
        vst[it] = Gp[(e>>7)*132 + (e&127)];
    }
    __syncthreads();

    // ---- Phase B: split P = G*2^-s into fp16 (h, l*2^11); init X = c12*P + c11*I
    {
        _Float16* Ph = (_Float16*)(sm + PH_OFF);
        _Float16* Pl = (_Float16*)(sm + PL_OFF);
        _Float16* Qh = (_Float16*)(sm + QTH_OFF);
        _Float16* Ql = (_Float16*)(sm + QTL_OFF);
        const float c12 = dC[12], c11 = dC[11];
        #pragma unroll
        for (int it = 0; it < 32; ++it) {
            const int e = tid + (it << 9);
            const int i = e >> 7, j = e & 127;
            const float p = vst[it] * scale;
            const _Float16 ph = (_Float16)p;
            const _Float16 pl = (_Float16)((p - (float)ph) * 2048.f);
            Ph[i*ROWH + j] = ph;
            Pl[i*ROWH + j] = pl;
            const float x = c12*p + ((i == j) ? c11 : 0.f);
            const _Float16 xh = (_Float16)x;
            const _Float16 xl = (_Float16)((x - (float)xh) * 2048.f);
            Qh[j*ROWH + i] = xh;   // X^T
            Ql[j*ROWH + i] = xl;
        }
    }
    __syncthreads();

    const int lid = tid & 63;
    const int wid = tid >> 6;          // 0..7
    const int wr = wid >> 2, wc = wid & 3;
    const int lr = lid & 15, g = lid >> 4;
    float* gout = out + (size_t)wg * (D*D);

    // ---- Horner: X <- P*X + c_k*I (degree-12 Taylor, theta=2)
    for (int kk = 10; kk >= 1; --kk)
        matmul_step<true, false, false>(sm, dC[kk], gout, wr, wc, lr, g);
    matmul_step<true, true, false>(sm, dC[0], gout, wr, wc, lr, g);

    if (nsq == 0) {   // tiny-norm blocks (incl. CLS)
        const _Float16* Xh = (const _Float16*)(sm + PH_OFF);
        const _Float16* Xl = (const _Float16*)(sm + PL_OFF);
        for (int it = 0; it < 32; ++it) {
            const int e = tid + (it << 9);
            const int i = e >> 7, j = e & 127;
            gout[e] = (float)Xh[i*ROWH + j] + (float)Xl[i*ROWH + j] * (1.0f/2048.0f);
        }
        return;
    }

    // ---- Squarings: X <- X*X; last one streams fp32 straight to HBM
    for (int t = 0; t < nsq - 1; ++t)
        matmul_step<true, true, false>(sm, 0.f, gout, wr, wc, lr, g);
    matmul_step<false, false, true>(sm, 0.f, gout, wr, wc, lr, g);
}

extern "C" void kernel_launch(void* const* d_in, const int* in_sizes, int n_in,
                              void* d_out, int out_size, void* d_ws, size_t ws_size,
                              hipStream_t stream) {
    (void)in_sizes; (void)n_in; (void)d_ws; (void)ws_size; (void)out_size;
    const float* gen = (const float*)d_in[1];   // [2,1,128,128] fp32
    float* out = (float*)d_out;                 // [1,1370,1,128,128] fp32
    liere_expm_mfma<<<NMAT, NT, 0, stream>>>(gen, out);
}

// Round 5
// 465.586 us; speedup vs baseline: 4.4940x; 1.1047x over previous
//
#include <hip/hip_runtime.h>
#include <math.h>

#define STEPS 37
#define NMAT  (STEPS*STEPS + 1)   // 1370
#define D     128
#define NT    512                 // 8 waves, 2 per SIMD

typedef _Float16 half8 __attribute__((ext_vector_type(8)));
typedef __fp16   fp16x2 __attribute__((ext_vector_type(2)));
typedef float    f32x4 __attribute__((ext_vector_type(4)));

// Swizzled row-major fp16 matrices: 256B rows (128 halves), 16 slots of 16B,
// slot index XOR'd with (row&7)  -> conflict-free fragment reads (G4/T2).
#define PH_OFF   0          // P high;  later X row-major high  (A-operand)
#define PL_OFF   32768      // P low*2^11; later X row-major low
#define QTH_OFF  65536      // X^T high (B-operand, K-contiguous)
#define QTL_OFF  98304      // X^T low
#define RED_OFF  131072
#define LDS_BYTES (131072 + 640)

// Taylor 1/k!, degree 7 (theta = 0.5)
__constant__ float dC[8] = {
    1.0f, 1.0f, 5.0e-1f, 1.6666666666666666e-1f, 4.1666666666666664e-2f,
    8.3333333333333332e-3f, 1.3888888888888889e-3f, 1.9841269841269841e-4f };

// Y = A*X (+ diagc*I). A rows from PH/PL; X cols from QTH/QTL (X^T rows).
// 8 waves: (wr 0..1) x (wc 0..3) own rows [wr*64,+64) x cols [wc*32,+32).
template<bool WQT, bool WXR, bool WGL>
__device__ __forceinline__ void matmul_step(unsigned char* sm, float diagc,
                                            float* __restrict__ gout,
                                            int wr, int wc, int lr, int g)
{
    f32x4 acc1[4][2] = {};   // h*h
    f32x4 acc2[4][2] = {};   // h*l' + l'*h   (l' = l * 2^11)

    #pragma unroll
    for (int ks = 0; ks < 4; ++ks) {
        const int slot = 4*ks + g;             // 16B k-slot within a row
        half8 ah[4], al[4];
        #pragma unroll
        for (int bi = 0; bi < 4; ++bi) {
            const int r = wr*64 + bi*16 + lr;
            const int off = r*256 + ((slot ^ (r & 7)) << 4);
            ah[bi] = *(const half8*)(sm + PH_OFF + off);
            al[bi] = *(const half8*)(sm + PL_OFF + off);
        }
        #pragma unroll
        for (int bj = 0; bj < 2; ++bj) {
            const int c = wc*32 + bj*16 + lr;
            const int off = c*256 + ((slot ^ (c & 7)) << 4);
            const half8 qh = *(const half8*)(sm + QTH_OFF + off);
            const half8 ql = *(const half8*)(sm + QTL_OFF + off);
            #pragma unroll
            for (int bi = 0; bi < 4; ++bi) {
                acc1[bi][bj] = __builtin_amdgcn_mfma_f32_16x16x32_f16(ah[bi], qh, acc1[bi][bj], 0, 0, 0);
                acc2[bi][bj] = __builtin_amdgcn_mfma_f32_16x16x32_f16(ah[bi], ql, acc2[bi][bj], 0, 0, 0);
                acc2[bi][bj] = __builtin_amdgcn_mfma_f32_16x16x32_f16(al[bi], qh, acc2[bi][bj], 0, 0, 0);
            }
        }
    }

    if (WGL) {   // last step: stream fp32 to HBM, no LDS writes/barriers
        #pragma unroll
        for (int bi = 0; bi < 4; ++bi)
            #pragma unroll
            for (int bj = 0; bj < 2; ++bj) {
                const int col = wc*32 + bj*16 + lr;
                const int r0  = wr*64 + bi*16 + 4*g;
                #pragma unroll
                for (int q = 0; q < 4; ++q)
                    gout[(r0+q)*D + col] = acc1[bi][bj][q] + acc2[bi][bj][q] * (1.0f/2048.0f);
            }
        return;
    }

    // Register-only split conversion BEFORE the barrier (overlaps other waves' MFMAs)
    uint2 uhv[4][2], ulv[4][2];
    #pragma unroll
    for (int bi = 0; bi < 4; ++bi) {
        #pragma unroll
        for (int bj = 0; bj < 2; ++bj) {
            const int col = wc*32 + bj*16 + lr;
            const int r0  = wr*64 + bi*16 + 4*g;
            float v[4];
            #pragma unroll
            for (int q = 0; q < 4; ++q)
                v[q] = acc1[bi][bj][q] + acc2[bi][bj][q] * (1.0f/2048.0f);
            if (wr*64 + bi*16 == wc*32 + bj*16) {   // wave-uniform: tile holds diagonal
                #pragma unroll
                for (int q = 0; q < 4; ++q)
                    if (r0 + q == col) v[q] += diagc;
            }
            const fp16x2 h01 = __builtin_amdgcn_cvt_pkrtz(v[0], v[1]);
            const fp16x2 h23 = __builtin_amdgcn_cvt_pkrtz(v[2], v[3]);
            const fp16x2 l01 = __builtin_amdgcn_cvt_pkrtz((v[0]-(float)h01[0])*2048.f,
                                                          (v[1]-(float)h01[1])*2048.f);
            const fp16x2 l23 = __builtin_amdgcn_cvt_pkrtz((v[2]-(float)h23[0])*2048.f,
                                                          (v[3]-(float)h23[1])*2048.f);
            union { fp16x2 h2[2]; uint2 u; } cvh, cvl;
            cvh.h2[0] = h01; cvh.h2[1] = h23;
            cvl.h2[0] = l01; cvl.h2[1] = l23;
            uhv[bi][bj] = cvh.u; ulv[bi][bj] = cvl.u;
        }
    }
    __syncthreads();   // all reads of P/X done before overwrite

    #pragma unroll
    for (int bi = 0; bi < 4; ++bi) {
        #pragma unroll
        for (int bj = 0; bj < 2; ++bj) {
            const int col = wc*32 + bj*16 + lr;
            const int r0  = wr*64 + bi*16 + 4*g;
            if (WQT) {   // X^T: b64 at row=col, k-bytes r0*2..+7 (swizzled slot)
                const int off = col*256 + (((r0 >> 3) ^ (col & 7)) << 4) + ((g & 1) << 3);
                *(uint2*)(sm + QTH_OFF + off) = uhv[bi][bj];
                *(uint2*)(sm + QTL_OFF + off) = ulv[bi][bj];
            }
            if (WXR) {   // X row-major: scattered u16 (transpose cost)
                union { uint2 u; _Float16 h[4]; } th, tl;
                th.u = uhv[bi][bj]; tl.u = ulv[bi][bj];
                #pragma unroll
                for (int q = 0; q < 4; ++q) {
                    const int rr = r0 + q;
                    const int off = rr*256 + ((((col >> 3) ^ (rr & 7))) << 4) + ((col & 7) << 1);
                    *(_Float16*)(sm + PH_OFF + off) = th.h[q];
                    *(_Float16*)(sm + PL_OFF + off) = tl.h[q];
                }
            }
        }
    }
    __syncthreads();   // writes visible before next step's reads
}

__global__ __launch_bounds__(NT, 1)
void liere_expm_mfma(const float* __restrict__ gen, float* __restrict__ out)
{
    __shared__ __align__(16) unsigned char sm[LDS_BYTES];
    const int tid = threadIdx.x;
    const int wg  = blockIdx.x;

    float px = 0.f, py = 0.f;
    if (wg > 0) {
        const int idx = wg - 1;
        px = (float)(idx / STEPS) * (1.0f/(STEPS-1));
        py = (float)(idx % STEPS) * (1.0f/(STEPS-1));
    }

    // ---- Phase 0: G = px*S0 + py*S1 (fp32), padded 132-float rows at sm+0
    float* Gp = (float*)sm;            // 128*132*4 = 67584 B (overlaps PH/PL/QTH head)
    const float* g0 = gen;
    const float* g1 = gen + D*D;
    for (int it = 0; it < 32; ++it) {
        const int e = tid + (it << 9);
        const int i = e >> 7, j = e & 127;
        if (i < j) {
            const float v = px*g0[e] + py*g1[e];
            Gp[i*132 + j] =  v;
            Gp[j*132 + i] = -v;
        } else if (i == j) {
            Gp[i*132 + j] = 0.f;
        }
    }
    __syncthreads();

    // ---- Phase 1: row abs-sums (= col sums for skew) -> tree max -> s
    float* red = (float*)(sm + RED_OFF);
    if (tid < D) {
        float s = 0.f;
        const f32x4* rowp = (const f32x4*)&Gp[tid*132];
        #pragma unroll 8
        for (int u = 0; u < 32; ++u) {
            const f32x4 v = rowp[u];
            s += fabsf(v.x) + fabsf(v.y) + fabsf(v.z) + fabsf(v.w);
        }
        red[tid] = s;
    }
    __syncthreads();
    #pragma unroll
    for (int off = 64; off >= 1; off >>= 1) {
        if (tid < off) red[tid] = fmaxf(red[tid], red[tid + off]);
        __syncthreads();
    }
    const float m = red[0];
    int nsq = 0;
    if (m > 0.5f) nsq = (int)ceilf(log2f(m * 2.0f));   // theta = 0.5
    if (nsq < 0) nsq = 0;
    const float scale = exp2f(-(float)nsq);

    // ---- Phase A: stash this lane's G values (regions about to be reused)
    float vst[32];
    #pragma unroll
    for (int it = 0; it < 32; ++it) {
        const int e = tid + (it << 9);
        vst[it] = Gp[(e>>7)*132 + (e&127)];
    }
    __syncthreads();

    // ---- Phase B: split P = G*2^-s into fp16 (h, l*2^11); init X = c7*P + c6*I
    {
        const float c7 = dC[7], c6 = dC[6];
        #pragma unroll
        for (int it = 0; it < 32; ++it) {
            const int e = tid + (it << 9);
            const int i = e >> 7, j = e & 127;
            const float p = vst[it] * scale;
            const _Float16 ph = (_Float16)p;
            const _Float16 pl = (_Float16)((p - (float)ph) * 2048.f);
            const int offP = i*256 + (((j >> 3) ^ (i & 7)) << 4) + ((j & 7) << 1);
            *(_Float16*)(sm + PH_OFF + offP) = ph;
            *(_Float16*)(sm + PL_OFF + offP) = pl;
            const float x = c7*p + ((i == j) ? c6 : 0.f);
            const _Float16 xh = (_Float16)x;
            const _Float16 xl = (_Float16)((x - (float)xh) * 2048.f);
            const int offQ = j*256 + (((i >> 3) ^ (j & 7)) << 4) + ((i & 7) << 1);
            *(_Float16*)(sm + QTH_OFF + offQ) = xh;   // X^T
            *(_Float16*)(sm + QTL_OFF + offQ) = xl;
        }
    }
    __syncthreads();

    const int lid = tid & 63;
    const int wid = tid >> 6;          // 0..7
    const int wr = wid >> 2, wc = wid & 3;
    const int lr = lid & 15, g = lid >> 4;
    float* gout = out + (size_t)wg * (D*D);

    // ---- Horner: X <- P*X + c_k*I (degree-7 Taylor, theta=0.5): 6 muls
    for (int kk = 5; kk >= 1; --kk)
        matmul_step<true, false, false>(sm, dC[kk], gout, wr, wc, lr, g);
    matmul_step<true, true, false>(sm, dC[0], gout, wr, wc, lr, g);

    if (nsq == 0) {   // tiny-norm blocks (incl. CLS)
        for (int it = 0; it < 32; ++it) {
            const int e = tid + (it << 9);
            const int i = e >> 7, j = e & 127;
            const int off = i*256 + (((j >> 3) ^ (i & 7)) << 4) + ((j & 7) << 1);
            gout[e] = (float)*(_Float16*)(sm + PH_OFF + off)
                    + (float)*(_Float16*)(sm + PL_OFF + off) * (1.0f/2048.0f);
        }
        return;
    }

    // ---- Squarings: X <- X*X; last one streams fp32 straight to HBM
    for (int t = 0; t < nsq - 1; ++t)
        matmul_step<true, true, false>(sm, 0.f, gout, wr, wc, lr, g);
    matmul_step<false, false, true>(sm, 0.f, gout, wr, wc, lr, g);
}

extern "C" void kernel_launch(void* const* d_in, const int* in_sizes, int n_in,
                              void* d_out, int out_size, void* d_ws, size_t ws_size,
                              hipStream_t stream) {
    (void)in_sizes; (void)n_in; (void)d_ws; (void)ws_size; (void)out_size;
    const float* gen = (const float*)d_in[1];   // [2,1,128,128] fp32
    float* out = (float*)d_out;                 // [1,1370,1,128,128] fp32
    liere_expm_mfma<<<NMAT, NT, 0, stream>>>(gen, out);
}